// Round 1
// baseline (617.630 us; speedup 1.0000x reference)
//
#include <hip/hip_runtime.h>
#include <type_traits>

// PerceiverAttentionCA on MI355X (gfx950).  Round 5:
//  - flash_attn: occupancy 2x via q-block 64 (4 waves x 16 q), kv-tile 32,
//    grid 1024, LDS 36 KB -> 4 blocks/CU (16 waves/CU).  Same double-buffered
//    1-barrier K/V staging, XCD head-clustering, exp2-space online softmax.
//  - gemm_bt: BK=64 (half the barriers, 32 KB LDS, same DMA volume).

using u16 = unsigned short;
using u32 = unsigned int;
typedef __attribute__((ext_vector_type(8))) short short8;   // 8 x bf16 bits
typedef __attribute__((ext_vector_type(4))) float floatx4;  // MFMA accumulator

typedef __attribute__((address_space(1))) const unsigned int gu32;
typedef __attribute__((address_space(3))) unsigned int lu32;

__device__ __forceinline__ void gld16(void* lds, const void* g) {
  __builtin_amdgcn_global_load_lds((gu32*)g, (lu32*)lds, 16, 0, 0);
}

__device__ inline u16 f2bf(float f) {
  u32 u = __float_as_uint(f);
  u32 r = (u + 0x7FFFu + ((u >> 16) & 1u)) >> 16;   // RNE
  return (u16)r;
}

// ---------------------------------------------------------------------------
// LayerNorm + cast to bf16.  One block (256 thr) per row.  L in {2048, 3072}.
// ---------------------------------------------------------------------------
template <int L>
__global__ __launch_bounds__(256) void ln_cast(const float* __restrict__ in,
                                               const float* __restrict__ gw,
                                               const float* __restrict__ bw,
                                               u16* __restrict__ out) {
  constexpr int C4 = L / 1024;
  const int row = blockIdx.x;
  const int t = threadIdx.x;
  const float* rp = in + (size_t)row * L;
  float4 v[C4];
  float s = 0.f, ss = 0.f;
#pragma unroll
  for (int c = 0; c < C4; ++c) {
    v[c] = *(const float4*)(rp + (c * 256 + t) * 4);
    s += v[c].x + v[c].y + v[c].z + v[c].w;
    ss += v[c].x * v[c].x + v[c].y * v[c].y + v[c].z * v[c].z + v[c].w * v[c].w;
  }
#pragma unroll
  for (int off = 32; off > 0; off >>= 1) {
    s += __shfl_down(s, off);
    ss += __shfl_down(ss, off);
  }
  __shared__ float red[8];
  const int wave = t >> 6, lane = t & 63;
  if (lane == 0) { red[wave] = s; red[4 + wave] = ss; }
  __syncthreads();
  const float tot = red[0] + red[1] + red[2] + red[3];
  const float tss = red[4] + red[5] + red[6] + red[7];
  const float mu = tot * (1.f / L);
  const float rstd = rsqrtf(tss * (1.f / L) - mu * mu + 1e-5f);
  u16* op = out + (size_t)row * L;
#pragma unroll
  for (int c = 0; c < C4; ++c) {
    const int base = (c * 256 + t) * 4;
    float4 gv = *(const float4*)(gw + base);
    float4 bv = *(const float4*)(bw + base);
    u32 p0 = (u32)f2bf((v[c].x - mu) * rstd * gv.x + bv.x) |
             ((u32)f2bf((v[c].y - mu) * rstd * gv.y + bv.y) << 16);
    u32 p1 = (u32)f2bf((v[c].z - mu) * rstd * gv.z + bv.z) |
             ((u32)f2bf((v[c].w - mu) * rstd * gv.w + bv.w) << 16);
    uint2 pk; pk.x = p0; pk.y = p1;
    *(uint2*)(op + base) = pk;
  }
}

// ---------------------------------------------------------------------------
// Transpose + cast: fp32 in (R x C) -> bf16 out (C x R).  Block (32,8).
// ---------------------------------------------------------------------------
__global__ __launch_bounds__(256) void transpose_cast(const float* __restrict__ in,
                                                      u16* __restrict__ out,
                                                      int R, int C) {
  __shared__ u16 tile[32][33];
  const int c0 = blockIdx.x * 32, r0 = blockIdx.y * 32;
  const int x = threadIdx.x, y = threadIdx.y;
#pragma unroll
  for (int j = 0; j < 4; ++j)
    tile[y + 8 * j][x] = f2bf(in[(size_t)(r0 + y + 8 * j) * C + c0 + x]);
  __syncthreads();
#pragma unroll
  for (int j = 0; j < 4; ++j)
    out[(size_t)(c0 + y + 8 * j) * R + r0 + x] = tile[x][y + 8 * j];
}

// ---------------------------------------------------------------------------
// Extract+transpose V from kv buffer -> vT (b,h,128,2048).
// ---------------------------------------------------------------------------
__global__ __launch_bounds__(256) void transpose_v(const u16* __restrict__ kvb,
                                                   u16* __restrict__ vT) {
  __shared__ u16 tile[32][33];
  const int bh = blockIdx.z, b = bh >> 4, h = bh & 15;
  const u16* src = kvb + (size_t)b * 2048 * 4096 + 2048 + h * 128;
  u16* dst = vT + (size_t)bh * 128 * 2048;
  const int d0 = blockIdx.x * 32, n0 = blockIdx.y * 32;
  const int x = threadIdx.x, y = threadIdx.y;
#pragma unroll
  for (int j = 0; j < 4; ++j)
    tile[y + 8 * j][x] = src[(size_t)(n0 + y + 8 * j) * 4096 + d0 + x];
  __syncthreads();
#pragma unroll
  for (int j = 0; j < 4; ++j)
    dst[(size_t)(d0 + y + 8 * j) * 2048 + n0 + x] = tile[x][y + 8 * j];
}

// ---------------------------------------------------------------------------
// GEMM  C(MxN) = A(MxK) * Bt(NxK)^T.  BK=64: global_load_lds width=16 into
// [128][64] tiles (32 KB), chunk-swizzle slot = chunk ^ (row&7) (2-way banks),
// half the barriers of BK=32.
// ---------------------------------------------------------------------------
template <typename OutT>
__global__ __launch_bounds__(256) void gemm_bt(const u16* __restrict__ A,
                                               const u16* __restrict__ Bt,
                                               OutT* __restrict__ C,
                                               int M, int N, int K) {
  __shared__ u16 As[128 * 64];
  __shared__ u16 Bs[128 * 64];
  const int tid = threadIdx.x;
  const int wave = tid >> 6, lane = tid & 63, l16 = lane & 15, quad = lane >> 4;
  const int wm = (wave >> 1) * 64, wn = (wave & 1) * 64;
  const long m0 = (long)blockIdx.y * 128, n0 = (long)blockIdx.x * 128;
  // staging: 4 chunks/thread/matrix: li = c*256+tid -> row = c*32 + (tid>>3),
  // lds slot = tid&7, global chunk = slot ^ (row&7) = (tid&7)^((tid>>3)&7)
  const int srow = tid >> 3;                          // 0..31
  const int gc = ((tid & 7) ^ ((tid >> 3) & 7)) * 8;  // u16 offset
  const u16* Ag0 = A + (m0 + srow) * (long)K + gc;
  const u16* Bg0 = Bt + (n0 + srow) * (long)K + gc;
  const long rowoff = 32L * K;

  const floatx4 fz = {0.f, 0.f, 0.f, 0.f};
  floatx4 acc[4][4];
#pragma unroll
  for (int i = 0; i < 4; ++i)
#pragma unroll
    for (int j = 0; j < 4; ++j) acc[i][j] = fz;

  for (int k0 = 0; k0 < K; k0 += 64) {
    __syncthreads();
#pragma unroll
    for (int c = 0; c < 4; ++c) {
      gld16(&As[(c * 256 + tid) * 8], Ag0 + c * rowoff + k0);
      gld16(&Bs[(c * 256 + tid) * 8], Bg0 + c * rowoff + k0);
    }
    __syncthreads();
#pragma unroll
    for (int kd = 0; kd < 2; ++kd) {
      const int sw = ((4 * kd + quad) ^ (l16 & 7)) * 8;
      short8 a[4], b[4];
#pragma unroll
      for (int i = 0; i < 4; ++i) a[i] = *(const short8*)&As[(wm + i * 16 + l16) * 64 + sw];
#pragma unroll
      for (int j = 0; j < 4; ++j) b[j] = *(const short8*)&Bs[(wn + j * 16 + l16) * 64 + sw];
#pragma unroll
      for (int i = 0; i < 4; ++i)
#pragma unroll
        for (int j = 0; j < 4; ++j)
          acc[i][j] = __builtin_amdgcn_mfma_f32_16x16x32_bf16(a[i], b[j], acc[i][j], 0, 0, 0);
    }
  }

#pragma unroll
  for (int i = 0; i < 4; ++i)
#pragma unroll
    for (int r = 0; r < 4; ++r) {
      const long row = m0 + wm + i * 16 + quad * 4 + r;
#pragma unroll
      for (int j = 0; j < 4; ++j) {
        const long col = n0 + wn + j * 16 + l16;
        if constexpr (std::is_same<OutT, float>::value)
          C[row * N + col] = acc[i][j][r];
        else
          C[row * N + col] = f2bf(acc[i][j][r]);
      }
    }
}

// ---------------------------------------------------------------------------
// Flash attention v4.  Grid 1024 blocks (XCD head-clustered), 4 waves,
// 16 q-rows/wave (q-block 64), kv-tile 32, DOUBLE-BUFFERED K/V.
// LDS 36 KB -> 4 blocks/CU (16 waves/CU, 2x the old occupancy).
// exp2-space online softmax; row-sum via ones-column MFMA.
// ---------------------------------------------------------------------------
__global__ __launch_bounds__(256, 4) void flash_attn(const u16* __restrict__ Q,
                                                     const u16* __restrict__ KV,
                                                     const u16* __restrict__ VT,
                                                     u16* __restrict__ O) {
  __shared__ u16 Ks[2][32 * 128];    // [kv][16 chunks], chunk ^= (kv&15)
  __shared__ u16 Vs[2][128 * 32];    // [d][4 chunks],   chunk ^= ((d>>1)&3)
  __shared__ u16 Ps[4][16 * 32];     // per-wave [q][4 chunks], chunk ^= ((q>>1)&3)
  const int tid = threadIdx.x;
  const int wave = tid >> 6, lane = tid & 63, l16 = lane & 15, quad = lane >> 4;
  // XCD head clustering: blocks with the same bh land on the same XCD (d%8).
  const int d = blockIdx.x;
  const int bh = (d & 7) * 4 + ((d >> 3) & 3);
  const int qt = d >> 5;                        // 0..31
  const int b = bh >> 4, h = bh & 15;
  const u16* Qb = Q + (size_t)b * 2048 * 2048 + h * 128;
  const u16* Kb = KV + (size_t)b * 2048 * 4096 + h * 128;
  const u16* Vb = VT + (size_t)bh * 128 * 2048;
  u16* Ob = O + (size_t)b * 2048 * 2048 + h * 128;
  const int q0 = qt * 64 + wave * 16;

  short8 qf[4];
#pragma unroll
  for (int kd = 0; kd < 4; ++kd)
    qf[kd] = *(const short8*)&Qb[(size_t)(q0 + l16) * 2048 + kd * 32 + quad * 8];

  short8 onesf;
  {
    union { short8 s; u32 w[4]; } uo;
    const u32 o = (l16 == 0) ? 0x3F803F80u : 0u;
#pragma unroll
    for (int i = 0; i < 4; ++i) uo.w[i] = o;
    onesf = uo.s;
  }

  const floatx4 fz = {0.f, 0.f, 0.f, 0.f};
  floatx4 oacc[9];
  float m[4];
#pragma unroll
  for (int jd = 0; jd < 9; ++jd) oacc[jd] = fz;
#pragma unroll
  for (int r = 0; r < 4; ++r) m[r] = -1e30f;

  u16* Psw = Ps[wave];
  const float sc2 = 0.12751775f;  // (1/sqrt(128)) * log2(e)
  const int sread = (l16 >> 1) & 3;  // read-side chunk swizzle for Ps and Vs

  auto stage = [&](int buf, int kv0) {
#pragma unroll
    for (int c = 0; c < 2; ++c) {
      const int li = c * 256 + tid;
      const int krow = li >> 4, kdb = (li & 15) ^ (krow & 15);
      gld16(&Ks[buf][li * 8], Kb + (size_t)(kv0 + krow) * 4096 + kdb * 8);
      const int vrow = li >> 2, vdb = (li & 3) ^ ((vrow >> 1) & 3);
      gld16(&Vs[buf][li * 8], Vb + (size_t)vrow * 2048 + kv0 + vdb * 8);
    }
  };

  stage(0, 0);
  int cur = 0;

  for (int kt = 0; kt < 64; ++kt) {
    __syncthreads();  // drains DMA for buf[cur]; syncs prev compute on buf[cur^1]
    if (kt < 63) stage(cur ^ 1, (kt + 1) * 32);
    const u16* Kc = Ks[cur];
    const u16* Vc = Vs[cur];

    // S = Q K^T : 1 q-tile x 2 kv-tiles
    floatx4 sacc[2];
#pragma unroll
    for (int jn = 0; jn < 2; ++jn) sacc[jn] = fz;
#pragma unroll
    for (int jn = 0; jn < 2; ++jn)
#pragma unroll
      for (int kd = 0; kd < 4; ++kd) {
        short8 kb = *(const short8*)&Kc[(jn * 16 + l16) * 128 + ((4 * kd + quad) ^ l16) * 8];
        sacc[jn] = __builtin_amdgcn_mfma_f32_16x16x32_bf16(qf[kd], kb, sacc[jn], 0, 0, 0);
      }

    // online softmax in exp2 space; write P (bf16) to swizzled LDS
#pragma unroll
    for (int r = 0; r < 4; ++r) {
      float mx = fmaxf(sacc[0][r], sacc[1][r]);
#pragma unroll
      for (int off = 8; off > 0; off >>= 1) mx = fmaxf(mx, __shfl_xor(mx, off, 16));
      const float mnew = fmaxf(m[r], sc2 * mx);
      const float alpha = __builtin_amdgcn_exp2f(m[r] - mnew);
      m[r] = mnew;
      const int q = quad * 4 + r;                 // 0..15
      const int mask = (q >> 1) & 3;
      u16* prow = &Psw[q * 32 + (l16 & 7)];
#pragma unroll
      for (int jn = 0; jn < 2; ++jn) {
        const float p = __builtin_amdgcn_exp2f(fmaf(sc2, sacc[jn][r], -mnew));
        const int slot = (2 * jn + (l16 >> 3)) ^ mask;
        prow[slot * 8] = f2bf(p);
      }
#pragma unroll
      for (int jd = 0; jd < 9; ++jd) oacc[jd][r] *= alpha;
    }

    // O += P V   (A = P frag from Ps, B = V frags from Vs; +ones col)
    short8 pf = *(const short8*)&Psw[l16 * 32 + (quad ^ ((l16 >> 1) & 3)) * 8];
#pragma unroll
    for (int jd = 0; jd < 8; ++jd) {
      short8 vb = *(const short8*)&Vc[(jd * 16 + l16) * 32 + (quad ^ sread) * 8];
      oacc[jd] = __builtin_amdgcn_mfma_f32_16x16x32_bf16(pf, vb, oacc[jd], 0, 0, 0);
    }
    oacc[8] = __builtin_amdgcn_mfma_f32_16x16x32_bf16(pf, onesf, oacc[8], 0, 0, 0);
    cur ^= 1;
  }

  // epilogue: l from ones-column; divide, store
#pragma unroll
  for (int r = 0; r < 4; ++r) {
    const float l = __shfl(oacc[8][r], lane & 48);
    const float inv = 1.f / l;
    const size_t row = q0 + quad * 4 + r;
#pragma unroll
    for (int jd = 0; jd < 8; ++jd)
      Ob[row * 2048 + jd * 16 + l16] = f2bf(oacc[jd][r] * inv);
  }
}

// ---------------------------------------------------------------------------
extern "C" void kernel_launch(void* const* d_in, const int* in_sizes, int n_in,
                              void* d_out, int out_size, void* d_ws, size_t ws_size,
                              hipStream_t stream) {
  const float* x       = (const float*)d_in[0];
  const float* latents = (const float*)d_in[1];
  const float* w_q     = (const float*)d_in[2];
  const float* w_kv    = (const float*)d_in[3];
  const float* w_out   = (const float*)d_in[4];
  const float* ln1_g   = (const float*)d_in[5];
  const float* ln1_b   = (const float*)d_in[6];
  const float* ln2_g   = (const float*)d_in[7];
  const float* ln2_b   = (const float*)d_in[8];

  char* ws = (char*)d_ws;
  u16* xn    = (u16*)(ws);              // LN(x)        [dead after kv gemm]
  u16* lnl   = (u16*)(ws + 16777216);   // LN(latents)  [dead after q gemm]
  u16* wqT   = (u16*)(ws + 41943040);
  u16* wkvT  = (u16*)(ws + 54525952);
  u16* woutT = (u16*)(ws + 71303168);
  u16* qb    = (u16*)(ws + 83886080);
  u16* kvb   = (u16*)(ws + 100663296);
  u16* vTb   = lnl;                     // alias
  u16* attn  = xn;                      // alias

  ln_cast<2048><<<dim3(4096), 256, 0, stream>>>(x, ln1_g, ln1_b, xn);
  ln_cast<3072><<<dim3(4096), 256, 0, stream>>>(latents, ln2_g, ln2_b, lnl);

  transpose_cast<<<dim3(64, 96), dim3(32, 8), 0, stream>>>(w_q, wqT, 3072, 2048);
  transpose_cast<<<dim3(128, 64), dim3(32, 8), 0, stream>>>(w_kv, wkvT, 2048, 4096);
  transpose_cast<<<dim3(96, 64), dim3(32, 8), 0, stream>>>(w_out, woutT, 2048, 3072);

  gemm_bt<u16><<<dim3(16, 32), 256, 0, stream>>>(lnl, wqT, qb, 4096, 2048, 3072);
  gemm_bt<u16><<<dim3(32, 32), 256, 0, stream>>>(xn, wkvT, kvb, 4096, 4096, 2048);

  transpose_v<<<dim3(4, 64, 32), dim3(32, 8), 0, stream>>>(kvb, vTb);

  flash_attn<<<dim3(1024), 256, 0, stream>>>(qb, kvb, vTb, attn);

  gemm_bt<float><<<dim3(24, 32), 256, 0, stream>>>(attn, woutT, (float*)d_out, 4096, 3072, 2048);
}

// Round 2
// 548.715 us; speedup vs baseline: 1.1256x; 1.1256x over previous
//
#include <hip/hip_runtime.h>
#include <type_traits>

// PerceiverAttentionCA on MI355X (gfx950).  Round 6:
//  - flash_attn: REVERT to round-4 structure (q-block 128, kv-tile 64,
//    grid 512, 80 KB LDS, 2 blocks/CU) -- round-5's smaller tiles doubled
//    barrier count + halved chain work and regressed 145.8 -> 170.8 us.
//  - NEW: T5 s_setprio(1) around QK^T and PV MFMA clusters (+4-7% attn, m191).
//  - NEW: T13 defer-max: skip O-rescale when tile max grows <= 8/ln2 in
//    exp2-space (wave-uniform __all branch; +5%, m214 v23).
//  - gemm_bt: unchanged (BK=64, 128^2, ~m97 structure).

using u16 = unsigned short;
using u32 = unsigned int;
typedef __attribute__((ext_vector_type(8))) short short8;   // 8 x bf16 bits
typedef __attribute__((ext_vector_type(4))) float floatx4;  // MFMA accumulator

typedef __attribute__((address_space(1))) const unsigned int gu32;
typedef __attribute__((address_space(3))) unsigned int lu32;

__device__ __forceinline__ void gld16(void* lds, const void* g) {
  __builtin_amdgcn_global_load_lds((gu32*)g, (lu32*)lds, 16, 0, 0);
}

__device__ inline u16 f2bf(float f) {
  u32 u = __float_as_uint(f);
  u32 r = (u + 0x7FFFu + ((u >> 16) & 1u)) >> 16;   // RNE
  return (u16)r;
}

// ---------------------------------------------------------------------------
// LayerNorm + cast to bf16.  One block (256 thr) per row.  L in {2048, 3072}.
// ---------------------------------------------------------------------------
template <int L>
__global__ __launch_bounds__(256) void ln_cast(const float* __restrict__ in,
                                               const float* __restrict__ gw,
                                               const float* __restrict__ bw,
                                               u16* __restrict__ out) {
  constexpr int C4 = L / 1024;
  const int row = blockIdx.x;
  const int t = threadIdx.x;
  const float* rp = in + (size_t)row * L;
  float4 v[C4];
  float s = 0.f, ss = 0.f;
#pragma unroll
  for (int c = 0; c < C4; ++c) {
    v[c] = *(const float4*)(rp + (c * 256 + t) * 4);
    s += v[c].x + v[c].y + v[c].z + v[c].w;
    ss += v[c].x * v[c].x + v[c].y * v[c].y + v[c].z * v[c].z + v[c].w * v[c].w;
  }
#pragma unroll
  for (int off = 32; off > 0; off >>= 1) {
    s += __shfl_down(s, off);
    ss += __shfl_down(ss, off);
  }
  __shared__ float red[8];
  const int wave = t >> 6, lane = t & 63;
  if (lane == 0) { red[wave] = s; red[4 + wave] = ss; }
  __syncthreads();
  const float tot = red[0] + red[1] + red[2] + red[3];
  const float tss = red[4] + red[5] + red[6] + red[7];
  const float mu = tot * (1.f / L);
  const float rstd = rsqrtf(tss * (1.f / L) - mu * mu + 1e-5f);
  u16* op = out + (size_t)row * L;
#pragma unroll
  for (int c = 0; c < C4; ++c) {
    const int base = (c * 256 + t) * 4;
    float4 gv = *(const float4*)(gw + base);
    float4 bv = *(const float4*)(bw + base);
    u32 p0 = (u32)f2bf((v[c].x - mu) * rstd * gv.x + bv.x) |
             ((u32)f2bf((v[c].y - mu) * rstd * gv.y + bv.y) << 16);
    u32 p1 = (u32)f2bf((v[c].z - mu) * rstd * gv.z + bv.z) |
             ((u32)f2bf((v[c].w - mu) * rstd * gv.w + bv.w) << 16);
    uint2 pk; pk.x = p0; pk.y = p1;
    *(uint2*)(op + base) = pk;
  }
}

// ---------------------------------------------------------------------------
// Transpose + cast: fp32 in (R x C) -> bf16 out (C x R).  Block (32,8).
// ---------------------------------------------------------------------------
__global__ __launch_bounds__(256) void transpose_cast(const float* __restrict__ in,
                                                      u16* __restrict__ out,
                                                      int R, int C) {
  __shared__ u16 tile[32][33];
  const int c0 = blockIdx.x * 32, r0 = blockIdx.y * 32;
  const int x = threadIdx.x, y = threadIdx.y;
#pragma unroll
  for (int j = 0; j < 4; ++j)
    tile[y + 8 * j][x] = f2bf(in[(size_t)(r0 + y + 8 * j) * C + c0 + x]);
  __syncthreads();
#pragma unroll
  for (int j = 0; j < 4; ++j)
    out[(size_t)(c0 + y + 8 * j) * R + r0 + x] = tile[x][y + 8 * j];
}

// ---------------------------------------------------------------------------
// Extract+transpose V from kv buffer -> vT (b,h,128,2048).
// ---------------------------------------------------------------------------
__global__ __launch_bounds__(256) void transpose_v(const u16* __restrict__ kvb,
                                                   u16* __restrict__ vT) {
  __shared__ u16 tile[32][33];
  const int bh = blockIdx.z, b = bh >> 4, h = bh & 15;
  const u16* src = kvb + (size_t)b * 2048 * 4096 + 2048 + h * 128;
  u16* dst = vT + (size_t)bh * 128 * 2048;
  const int d0 = blockIdx.x * 32, n0 = blockIdx.y * 32;
  const int x = threadIdx.x, y = threadIdx.y;
#pragma unroll
  for (int j = 0; j < 4; ++j)
    tile[y + 8 * j][x] = src[(size_t)(n0 + y + 8 * j) * 4096 + d0 + x];
  __syncthreads();
#pragma unroll
  for (int j = 0; j < 4; ++j)
    dst[(size_t)(d0 + y + 8 * j) * 2048 + n0 + x] = tile[x][y + 8 * j];
}

// ---------------------------------------------------------------------------
// GEMM  C(MxN) = A(MxK) * Bt(NxK)^T.  BK=64: global_load_lds width=16 into
// [128][64] tiles (32 KB), chunk-swizzle slot = chunk ^ (row&7) (2-way banks),
// half the barriers of BK=32.
// ---------------------------------------------------------------------------
template <typename OutT>
__global__ __launch_bounds__(256) void gemm_bt(const u16* __restrict__ A,
                                               const u16* __restrict__ Bt,
                                               OutT* __restrict__ C,
                                               int M, int N, int K) {
  __shared__ u16 As[128 * 64];
  __shared__ u16 Bs[128 * 64];
  const int tid = threadIdx.x;
  const int wave = tid >> 6, lane = tid & 63, l16 = lane & 15, quad = lane >> 4;
  const int wm = (wave >> 1) * 64, wn = (wave & 1) * 64;
  const long m0 = (long)blockIdx.y * 128, n0 = (long)blockIdx.x * 128;
  // staging: 4 chunks/thread/matrix: li = c*256+tid -> row = c*32 + (tid>>3),
  // lds slot = tid&7, global chunk = slot ^ (row&7) = (tid&7)^((tid>>3)&7)
  const int srow = tid >> 3;                          // 0..31
  const int gc = ((tid & 7) ^ ((tid >> 3) & 7)) * 8;  // u16 offset
  const u16* Ag0 = A + (m0 + srow) * (long)K + gc;
  const u16* Bg0 = Bt + (n0 + srow) * (long)K + gc;
  const long rowoff = 32L * K;

  const floatx4 fz = {0.f, 0.f, 0.f, 0.f};
  floatx4 acc[4][4];
#pragma unroll
  for (int i = 0; i < 4; ++i)
#pragma unroll
    for (int j = 0; j < 4; ++j) acc[i][j] = fz;

  for (int k0 = 0; k0 < K; k0 += 64) {
    __syncthreads();
#pragma unroll
    for (int c = 0; c < 4; ++c) {
      gld16(&As[(c * 256 + tid) * 8], Ag0 + c * rowoff + k0);
      gld16(&Bs[(c * 256 + tid) * 8], Bg0 + c * rowoff + k0);
    }
    __syncthreads();
#pragma unroll
    for (int kd = 0; kd < 2; ++kd) {
      const int sw = ((4 * kd + quad) ^ (l16 & 7)) * 8;
      short8 a[4], b[4];
#pragma unroll
      for (int i = 0; i < 4; ++i) a[i] = *(const short8*)&As[(wm + i * 16 + l16) * 64 + sw];
#pragma unroll
      for (int j = 0; j < 4; ++j) b[j] = *(const short8*)&Bs[(wn + j * 16 + l16) * 64 + sw];
#pragma unroll
      for (int i = 0; i < 4; ++i)
#pragma unroll
        for (int j = 0; j < 4; ++j)
          acc[i][j] = __builtin_amdgcn_mfma_f32_16x16x32_bf16(a[i], b[j], acc[i][j], 0, 0, 0);
    }
  }

#pragma unroll
  for (int i = 0; i < 4; ++i)
#pragma unroll
    for (int r = 0; r < 4; ++r) {
      const long row = m0 + wm + i * 16 + quad * 4 + r;
#pragma unroll
      for (int j = 0; j < 4; ++j) {
        const long col = n0 + wn + j * 16 + l16;
        if constexpr (std::is_same<OutT, float>::value)
          C[row * N + col] = acc[i][j][r];
        else
          C[row * N + col] = f2bf(acc[i][j][r]);
      }
    }
}

// ---------------------------------------------------------------------------
// Flash attention v5 (= v3 structure + setprio + defer-max).
// Grid 512 blocks (XCD head-clustered), 4 waves, 32 q-rows/wave, kv-tile 64,
// DOUBLE-BUFFERED K/V (80 KB LDS, 2 blocks/CU).
// exp2-space online softmax; row-sum via ones-column MFMA.
// ---------------------------------------------------------------------------
__global__ __launch_bounds__(256, 2) void flash_attn(const u16* __restrict__ Q,
                                                     const u16* __restrict__ KV,
                                                     const u16* __restrict__ VT,
                                                     u16* __restrict__ O) {
  __shared__ u16 Ks[2][64 * 128];    // [kv][16 chunks], chunk^= (kv&15)
  __shared__ u16 Vs[2][128 * 64];    // [d][8 chunks],   chunk^= (d&7)
  __shared__ u16 Ps[4][32 * 64];     // per-wave [q][8 chunks], chunk^=((q&7)^(q>>3))
  const int tid = threadIdx.x;
  const int wave = tid >> 6, lane = tid & 63, l16 = lane & 15, quad = lane >> 4;
  // XCD head clustering: blocks with the same bh land on the same XCD (d%8).
  const int d = blockIdx.x;
  const int bh = (d & 7) * 4 + ((d >> 3) & 3);
  const int qt = d >> 5;
  const int b = bh >> 4, h = bh & 15;
  const u16* Qb = Q + (size_t)b * 2048 * 2048 + h * 128;
  const u16* Kb = KV + (size_t)b * 2048 * 4096 + h * 128;
  const u16* Vb = VT + (size_t)bh * 128 * 2048;
  u16* Ob = O + (size_t)b * 2048 * 2048 + h * 128;
  const int q0 = qt * 128 + wave * 32;

  short8 qf[2][4];
#pragma unroll
  for (int t = 0; t < 2; ++t)
#pragma unroll
    for (int kd = 0; kd < 4; ++kd)
      qf[t][kd] = *(const short8*)&Qb[(size_t)(q0 + t * 16 + l16) * 2048 + kd * 32 + quad * 8];

  short8 onesf;
  {
    union { short8 s; u32 w[4]; } uo;
    const u32 o = (l16 == 0) ? 0x3F803F80u : 0u;
#pragma unroll
    for (int i = 0; i < 4; ++i) uo.w[i] = o;
    onesf = uo.s;
  }

  const floatx4 fz = {0.f, 0.f, 0.f, 0.f};
  floatx4 oacc[2][9];
  float m[2][4];
#pragma unroll
  for (int t = 0; t < 2; ++t) {
#pragma unroll
    for (int jd = 0; jd < 9; ++jd) oacc[t][jd] = fz;
#pragma unroll
    for (int r = 0; r < 4; ++r) m[t][r] = -1e30f;
  }

  u16* Psw = Ps[wave];
  const float sc2 = 0.12751775f;   // (1/sqrt(128)) * log2(e)
  const float THR2 = 11.5416f;     // defer-max threshold 8 in ln-space -> log2

  auto stage = [&](int buf, int kv0) {
#pragma unroll
    for (int c = 0; c < 4; ++c) {
      const int li = c * 256 + tid;
      const int krow = li >> 4, kdb = (li & 15) ^ (krow & 15);
      gld16(&Ks[buf][li * 8], Kb + (size_t)(kv0 + krow) * 4096 + kdb * 8);
      const int vrow = li >> 3, vdb = (li & 7) ^ (vrow & 7);
      gld16(&Vs[buf][li * 8], Vb + (size_t)vrow * 2048 + kv0 + vdb * 8);
    }
  };

  stage(0, 0);
  int cur = 0;

  for (int kt = 0; kt < 32; ++kt) {
    __syncthreads();  // drains DMA for buf[cur]; syncs prev compute on buf[cur^1]
    if (kt < 31) stage(cur ^ 1, (kt + 1) * 64);
    const u16* Kc = Ks[cur];
    const u16* Vc = Vs[cur];

    // S = Q K^T : 2 q-tiles x 4 kv-tiles
    floatx4 sacc[2][4];
#pragma unroll
    for (int t = 0; t < 2; ++t)
#pragma unroll
      for (int jn = 0; jn < 4; ++jn) sacc[t][jn] = fz;
    __builtin_amdgcn_s_setprio(1);
#pragma unroll
    for (int jn = 0; jn < 4; ++jn)
#pragma unroll
      for (int kd = 0; kd < 4; ++kd) {
        short8 kb = *(const short8*)&Kc[(jn * 16 + l16) * 128 + ((4 * kd + quad) ^ l16) * 8];
        sacc[0][jn] = __builtin_amdgcn_mfma_f32_16x16x32_bf16(qf[0][kd], kb, sacc[0][jn], 0, 0, 0);
        sacc[1][jn] = __builtin_amdgcn_mfma_f32_16x16x32_bf16(qf[1][kd], kb, sacc[1][jn], 0, 0, 0);
      }
    __builtin_amdgcn_s_setprio(0);

    // online softmax in exp2 space; write P (bf16) to swizzled LDS.
    // defer-max (T13): keep old running max (skip O-rescale) unless some row's
    // tile max exceeds it by >8/ln2; P then bounded by 2^11.54 (bf16-safe, and
    // the ones-column denominator scales identically so the ratio is exact).
#pragma unroll
    for (int t = 0; t < 2; ++t) {
#pragma unroll
      for (int r = 0; r < 4; ++r) {
        float mx = fmaxf(fmaxf(sacc[t][0][r], sacc[t][1][r]),
                         fmaxf(sacc[t][2][r], sacc[t][3][r]));
#pragma unroll
        for (int off = 8; off > 0; off >>= 1) mx = fmaxf(mx, __shfl_xor(mx, off, 16));
        const float mxs = sc2 * mx;
        if (!__all(mxs - m[t][r] <= THR2)) {
          const float mnew = fmaxf(m[t][r], mxs);
          const float alpha = __builtin_amdgcn_exp2f(m[t][r] - mnew);
          m[t][r] = mnew;
#pragma unroll
          for (int jd = 0; jd < 9; ++jd) oacc[t][jd][r] *= alpha;
        }
        const float mrow = m[t][r];
        const int q = t * 16 + quad * 4 + r;               // 0..31
        const int mask = (q & 7) ^ (q >> 3);
        u16* prow = &Psw[q * 64 + (l16 & 7)];
#pragma unroll
        for (int jn = 0; jn < 4; ++jn) {
          const float p = __builtin_amdgcn_exp2f(fmaf(sc2, sacc[t][jn][r], -mrow));
          const int slot = (2 * jn + (l16 >> 3)) ^ mask;
          prow[slot * 8] = f2bf(p);
        }
      }
    }

    // O += P V   (A = P frags from Ps, B = V frags from Vs; +ones col)
    const int pmask0 = (l16 & 7) ^ (l16 >> 3);        // t=0
    const int pmask1 = (l16 & 7) ^ (2 + (l16 >> 3));  // t=1
    __builtin_amdgcn_s_setprio(1);
#pragma unroll
    for (int kk = 0; kk < 2; ++kk) {
      const int chunk = 4 * kk + quad;
      short8 pf0 = *(const short8*)&Psw[(l16) * 64 + (chunk ^ pmask0) * 8];
      short8 pf1 = *(const short8*)&Psw[(16 + l16) * 64 + (chunk ^ pmask1) * 8];
#pragma unroll
      for (int jd = 0; jd < 8; ++jd) {
        short8 vb = *(const short8*)&Vc[(jd * 16 + l16) * 64 + (chunk ^ (l16 & 7)) * 8];
        oacc[0][jd] = __builtin_amdgcn_mfma_f32_16x16x32_bf16(pf0, vb, oacc[0][jd], 0, 0, 0);
        oacc[1][jd] = __builtin_amdgcn_mfma_f32_16x16x32_bf16(pf1, vb, oacc[1][jd], 0, 0, 0);
      }
      oacc[0][8] = __builtin_amdgcn_mfma_f32_16x16x32_bf16(pf0, onesf, oacc[0][8], 0, 0, 0);
      oacc[1][8] = __builtin_amdgcn_mfma_f32_16x16x32_bf16(pf1, onesf, oacc[1][8], 0, 0, 0);
    }
    __builtin_amdgcn_s_setprio(0);
    cur ^= 1;
  }

  // epilogue: l from ones-column; divide, store
#pragma unroll
  for (int t = 0; t < 2; ++t)
#pragma unroll
    for (int r = 0; r < 4; ++r) {
      const float l = __shfl(oacc[t][8][r], lane & 48);
      const float inv = 1.f / l;
      const size_t row = q0 + t * 16 + quad * 4 + r;
#pragma unroll
      for (int jd = 0; jd < 8; ++jd)
        Ob[row * 2048 + jd * 16 + l16] = f2bf(oacc[t][jd][r] * inv);
    }
}

// ---------------------------------------------------------------------------
extern "C" void kernel_launch(void* const* d_in, const int* in_sizes, int n_in,
                              void* d_out, int out_size, void* d_ws, size_t ws_size,
                              hipStream_t stream) {
  const float* x       = (const float*)d_in[0];
  const float* latents = (const float*)d_in[1];
  const float* w_q     = (const float*)d_in[2];
  const float* w_kv    = (const float*)d_in[3];
  const float* w_out   = (const float*)d_in[4];
  const float* ln1_g   = (const float*)d_in[5];
  const float* ln1_b   = (const float*)d_in[6];
  const float* ln2_g   = (const float*)d_in[7];
  const float* ln2_b   = (const float*)d_in[8];

  char* ws = (char*)d_ws;
  u16* xn    = (u16*)(ws);              // LN(x)        [dead after kv gemm]
  u16* lnl   = (u16*)(ws + 16777216);   // LN(latents)  [dead after q gemm]
  u16* wqT   = (u16*)(ws + 41943040);
  u16* wkvT  = (u16*)(ws + 54525952);
  u16* woutT = (u16*)(ws + 71303168);
  u16* qb    = (u16*)(ws + 83886080);
  u16* kvb   = (u16*)(ws + 100663296);
  u16* vTb   = lnl;                     // alias
  u16* attn  = xn;                      // alias

  ln_cast<2048><<<dim3(4096), 256, 0, stream>>>(x, ln1_g, ln1_b, xn);
  ln_cast<3072><<<dim3(4096), 256, 0, stream>>>(latents, ln2_g, ln2_b, lnl);

  transpose_cast<<<dim3(64, 96), dim3(32, 8), 0, stream>>>(w_q, wqT, 3072, 2048);
  transpose_cast<<<dim3(128, 64), dim3(32, 8), 0, stream>>>(w_kv, wkvT, 2048, 4096);
  transpose_cast<<<dim3(96, 64), dim3(32, 8), 0, stream>>>(w_out, woutT, 2048, 3072);

  gemm_bt<u16><<<dim3(16, 32), 256, 0, stream>>>(lnl, wqT, qb, 4096, 2048, 3072);
  gemm_bt<u16><<<dim3(32, 32), 256, 0, stream>>>(xn, wkvT, kvb, 4096, 4096, 2048);

  transpose_v<<<dim3(4, 64, 32), dim3(32, 8), 0, stream>>>(kvb, vTb);

  flash_attn<<<dim3(512), 256, 0, stream>>>(qb, kvb, vTb, attn);

  gemm_bt<float><<<dim3(24, 32), 256, 0, stream>>>(attn, woutT, (float*)d_out, 4096, 3072, 2048);
}

// Round 3
// 513.259 us; speedup vs baseline: 1.2033x; 1.0691x over previous
//
#include <hip/hip_runtime.h>
#include <type_traits>

// PerceiverAttentionCA on MI355X (gfx950).  Round 7:
//  - NEW gemm_bt8: 256x256 8-phase GEMM (plain-HIP port of the HK/m201
//    template): 512 thr / 8 waves, BK=64, double-buffered 128 KiB LDS,
//    per-phase {ds_read | 1 half-tile gld16 | bar | setprio MFMA | counted
//    vmcnt | bar}, quadrant-per-phase so half-tiles land in need order
//    (A0,B0,B1,A1), vmcnt(4) never drains mid-loop.  Used for the kv and
//    out GEMMs (256/192 wgs).  q GEMM stays on the 128^2 kernel (N=2048
//    would fill only half the CUs at 256^2).
//  - flash_attn: unchanged from round 6 (133 us: setprio + defer-max).

using u16 = unsigned short;
using u32 = unsigned int;
typedef __attribute__((ext_vector_type(8))) short short8;   // 8 x bf16 bits
typedef __attribute__((ext_vector_type(4))) float floatx4;  // MFMA accumulator

typedef __attribute__((address_space(1))) const unsigned int gu32;
typedef __attribute__((address_space(3))) unsigned int lu32;

__device__ __forceinline__ void gld16(void* lds, const void* g) {
  __builtin_amdgcn_global_load_lds((gu32*)g, (lu32*)lds, 16, 0, 0);
}

__device__ inline u16 f2bf(float f) {
  u32 u = __float_as_uint(f);
  u32 r = (u + 0x7FFFu + ((u >> 16) & 1u)) >> 16;   // RNE
  return (u16)r;
}

// ---------------------------------------------------------------------------
// LayerNorm + cast to bf16.  One block (256 thr) per row.  L in {2048, 3072}.
// ---------------------------------------------------------------------------
template <int L>
__global__ __launch_bounds__(256) void ln_cast(const float* __restrict__ in,
                                               const float* __restrict__ gw,
                                               const float* __restrict__ bw,
                                               u16* __restrict__ out) {
  constexpr int C4 = L / 1024;
  const int row = blockIdx.x;
  const int t = threadIdx.x;
  const float* rp = in + (size_t)row * L;
  float4 v[C4];
  float s = 0.f, ss = 0.f;
#pragma unroll
  for (int c = 0; c < C4; ++c) {
    v[c] = *(const float4*)(rp + (c * 256 + t) * 4);
    s += v[c].x + v[c].y + v[c].z + v[c].w;
    ss += v[c].x * v[c].x + v[c].y * v[c].y + v[c].z * v[c].z + v[c].w * v[c].w;
  }
#pragma unroll
  for (int off = 32; off > 0; off >>= 1) {
    s += __shfl_down(s, off);
    ss += __shfl_down(ss, off);
  }
  __shared__ float red[8];
  const int wave = t >> 6, lane = t & 63;
  if (lane == 0) { red[wave] = s; red[4 + wave] = ss; }
  __syncthreads();
  const float tot = red[0] + red[1] + red[2] + red[3];
  const float tss = red[4] + red[5] + red[6] + red[7];
  const float mu = tot * (1.f / L);
  const float rstd = rsqrtf(tss * (1.f / L) - mu * mu + 1e-5f);
  u16* op = out + (size_t)row * L;
#pragma unroll
  for (int c = 0; c < C4; ++c) {
    const int base = (c * 256 + t) * 4;
    float4 gv = *(const float4*)(gw + base);
    float4 bv = *(const float4*)(bw + base);
    u32 p0 = (u32)f2bf((v[c].x - mu) * rstd * gv.x + bv.x) |
             ((u32)f2bf((v[c].y - mu) * rstd * gv.y + bv.y) << 16);
    u32 p1 = (u32)f2bf((v[c].z - mu) * rstd * gv.z + bv.z) |
             ((u32)f2bf((v[c].w - mu) * rstd * gv.w + bv.w) << 16);
    uint2 pk; pk.x = p0; pk.y = p1;
    *(uint2*)(op + base) = pk;
  }
}

// ---------------------------------------------------------------------------
// Transpose + cast: fp32 in (R x C) -> bf16 out (C x R).  Block (32,8).
// ---------------------------------------------------------------------------
__global__ __launch_bounds__(256) void transpose_cast(const float* __restrict__ in,
                                                      u16* __restrict__ out,
                                                      int R, int C) {
  __shared__ u16 tile[32][33];
  const int c0 = blockIdx.x * 32, r0 = blockIdx.y * 32;
  const int x = threadIdx.x, y = threadIdx.y;
#pragma unroll
  for (int j = 0; j < 4; ++j)
    tile[y + 8 * j][x] = f2bf(in[(size_t)(r0 + y + 8 * j) * C + c0 + x]);
  __syncthreads();
#pragma unroll
  for (int j = 0; j < 4; ++j)
    out[(size_t)(c0 + y + 8 * j) * R + r0 + x] = tile[x][y + 8 * j];
}

// ---------------------------------------------------------------------------
// Extract+transpose V from kv buffer -> vT (b,h,128,2048).
// ---------------------------------------------------------------------------
__global__ __launch_bounds__(256) void transpose_v(const u16* __restrict__ kvb,
                                                   u16* __restrict__ vT) {
  __shared__ u16 tile[32][33];
  const int bh = blockIdx.z, b = bh >> 4, h = bh & 15;
  const u16* src = kvb + (size_t)b * 2048 * 4096 + 2048 + h * 128;
  u16* dst = vT + (size_t)bh * 128 * 2048;
  const int d0 = blockIdx.x * 32, n0 = blockIdx.y * 32;
  const int x = threadIdx.x, y = threadIdx.y;
#pragma unroll
  for (int j = 0; j < 4; ++j)
    tile[y + 8 * j][x] = src[(size_t)(n0 + y + 8 * j) * 4096 + d0 + x];
  __syncthreads();
#pragma unroll
  for (int j = 0; j < 4; ++j)
    dst[(size_t)(d0 + y + 8 * j) * 2048 + n0 + x] = tile[x][y + 8 * j];
}

// ---------------------------------------------------------------------------
// GEMM  C(MxN) = A(MxK) * Bt(NxK)^T.  128^2 tile, BK=64 (q GEMM only).
// ---------------------------------------------------------------------------
template <typename OutT>
__global__ __launch_bounds__(256) void gemm_bt(const u16* __restrict__ A,
                                               const u16* __restrict__ Bt,
                                               OutT* __restrict__ C,
                                               int M, int N, int K) {
  __shared__ u16 As[128 * 64];
  __shared__ u16 Bs[128 * 64];
  const int tid = threadIdx.x;
  const int wave = tid >> 6, lane = tid & 63, l16 = lane & 15, quad = lane >> 4;
  const int wm = (wave >> 1) * 64, wn = (wave & 1) * 64;
  const long m0 = (long)blockIdx.y * 128, n0 = (long)blockIdx.x * 128;
  const int srow = tid >> 3;                          // 0..31
  const int gc = ((tid & 7) ^ ((tid >> 3) & 7)) * 8;  // u16 offset
  const u16* Ag0 = A + (m0 + srow) * (long)K + gc;
  const u16* Bg0 = Bt + (n0 + srow) * (long)K + gc;
  const long rowoff = 32L * K;

  const floatx4 fz = {0.f, 0.f, 0.f, 0.f};
  floatx4 acc[4][4];
#pragma unroll
  for (int i = 0; i < 4; ++i)
#pragma unroll
    for (int j = 0; j < 4; ++j) acc[i][j] = fz;

  for (int k0 = 0; k0 < K; k0 += 64) {
    __syncthreads();
#pragma unroll
    for (int c = 0; c < 4; ++c) {
      gld16(&As[(c * 256 + tid) * 8], Ag0 + c * rowoff + k0);
      gld16(&Bs[(c * 256 + tid) * 8], Bg0 + c * rowoff + k0);
    }
    __syncthreads();
#pragma unroll
    for (int kd = 0; kd < 2; ++kd) {
      const int sw = ((4 * kd + quad) ^ (l16 & 7)) * 8;
      short8 a[4], b[4];
#pragma unroll
      for (int i = 0; i < 4; ++i) a[i] = *(const short8*)&As[(wm + i * 16 + l16) * 64 + sw];
#pragma unroll
      for (int j = 0; j < 4; ++j) b[j] = *(const short8*)&Bs[(wn + j * 16 + l16) * 64 + sw];
#pragma unroll
      for (int i = 0; i < 4; ++i)
#pragma unroll
        for (int j = 0; j < 4; ++j)
          acc[i][j] = __builtin_amdgcn_mfma_f32_16x16x32_bf16(a[i], b[j], acc[i][j], 0, 0, 0);
    }
  }

#pragma unroll
  for (int i = 0; i < 4; ++i)
#pragma unroll
    for (int r = 0; r < 4; ++r) {
      const long row = m0 + wm + i * 16 + quad * 4 + r;
#pragma unroll
      for (int j = 0; j < 4; ++j) {
        const long col = n0 + wn + j * 16 + l16;
        if constexpr (std::is_same<OutT, float>::value)
          C[row * N + col] = acc[i][j][r];
        else
          C[row * N + col] = f2bf(acc[i][j][r]);
      }
    }
}

// ---------------------------------------------------------------------------
// 8-phase 256x256 GEMM  C(MxN) = A(MxK) * Bt(NxK)^T.   512 thr, 8 waves.
// LDS: 2 bufs x [2 halves][128][64] per matrix = 128 KiB, 1 block/CU.
// Phase p computes block-C quadrant (mh=p>>1, nh=p&1): all 8 waves work the
// same quadrant (wave = 4x2: 32-row x 64-col piece), so phase p needs only
// {A-half mh, B-half nh}.  Stage order A0,B0,B1,A1 (1 half-tile = 2 gld16/thr
// per phase) matches need order; counted vmcnt(4) (never 0 mid-loop) before
// the closing barrier of phases 0/1/3 guarantees landing:
//   entering tile t: in-flight = {B1(t), A1(t)} (4 loads)
//   p0: +A0(t+1)=6, MFMA, vmcnt(4) -> B1(t) landed
//   p1: +B0(t+1)=6, MFMA, vmcnt(4) -> A1(t) landed
//   p2: +B1(t+1)=6, MFMA, no wait
//   p3: +A1(t+1)=8, MFMA, vmcnt(4) -> A0,B0(t+1) landed  -> invariant
// Raw s_barrier (no drain); setprio(1) around each 16-MFMA cluster.
// ---------------------------------------------------------------------------
#define GBAR()                                         \
  do {                                                 \
    asm volatile("" ::: "memory");                     \
    __builtin_amdgcn_s_barrier();                      \
    asm volatile("" ::: "memory");                     \
  } while (0)
#define VMW(N) asm volatile("s_waitcnt vmcnt(" #N ")" ::: "memory")

#define G8_LDA(MH)                                                             \
  {                                                                            \
    const u16* Ab_ = &As[buf][(MH) * 8192 + (wr * 32 + l16) * 64];             \
    _Pragma("unroll") for (int mi = 0; mi < 2; ++mi)                           \
    _Pragma("unroll") for (int ks = 0; ks < 2; ++ks)                           \
      af[mi][ks] = *(const short8*)&Ab_[mi * 1024 + ((4 * ks + quad) ^ swz) * 8]; \
  }
#define G8_LDB(DST, NH)                                                        \
  {                                                                            \
    const u16* Bb_ = &Bs[buf][(NH) * 8192 + (wc * 64 + l16) * 64];             \
    _Pragma("unroll") for (int ni = 0; ni < 4; ++ni)                           \
    _Pragma("unroll") for (int ks = 0; ks < 2; ++ks)                           \
      DST[ni][ks] = *(const short8*)&Bb_[ni * 1024 + ((4 * ks + quad) ^ swz) * 8]; \
  }
#define G8_MFMA(MH, BFX, NH)                                                   \
  __builtin_amdgcn_s_setprio(1);                                               \
  _Pragma("unroll") for (int ks = 0; ks < 2; ++ks)                             \
  _Pragma("unroll") for (int mi = 0; mi < 2; ++mi)                             \
  _Pragma("unroll") for (int ni = 0; ni < 4; ++ni)                             \
    acc[MH][mi][NH][ni] = __builtin_amdgcn_mfma_f32_16x16x32_bf16(             \
        af[mi][ks], BFX[ni][ks], acc[MH][mi][NH][ni], 0, 0, 0);                \
  __builtin_amdgcn_s_setprio(0);

template <typename OutT>
__global__ __launch_bounds__(512, 2) void gemm_bt8(const u16* __restrict__ A,
                                                   const u16* __restrict__ Bt,
                                                   OutT* __restrict__ C,
                                                   int M, int N, int K) {
  __shared__ u16 As[2][16384];   // [buf][half][128][64]
  __shared__ u16 Bs[2][16384];
  (void)M;
  const int tid = threadIdx.x;
  const int wave = tid >> 6, lane = tid & 63, l16 = lane & 15, quad = lane >> 4;
  const int wr = wave >> 1;      // 0..3: 32-row strip within the 128-row half
  const int wc = wave & 1;       // 0..1: 64-col strip within the 128-col half
  // XCD-aware bijective swizzle (nwg % 8 == 0 for all our grids)
  const int nwg = gridDim.x * gridDim.y;
  const int bid0 = blockIdx.y * gridDim.x + blockIdx.x;
  const int bid = (bid0 & 7) * (nwg >> 3) + (bid0 >> 3);
  const int bx = bid % gridDim.x, by = bid / gridDim.x;
  const long m0 = (long)by * 256, n0 = (long)bx * 256;

  // staging: half-tile = 128 rows x 64 k of one matrix; li = c*512+tid,
  // row = c*64 + (tid>>3), lds slot = tid&7, global chunk = slot ^ (row&7).
  const int srow = tid >> 3;                       // 0..63
  const int gc = ((tid & 7) ^ (srow & 7)) * 8;     // u16 offset

  auto stageA = [&](int bufn, int h, int k0) {
#pragma unroll
    for (int c = 0; c < 2; ++c)
      gld16(&As[bufn][h * 8192 + (c * 512 + tid) * 8],
            A + (size_t)(m0 + h * 128 + c * 64 + srow) * K + k0 + gc);
  };
  auto stageB = [&](int bufn, int h, int k0) {
#pragma unroll
    for (int c = 0; c < 2; ++c)
      gld16(&Bs[bufn][h * 8192 + (c * 512 + tid) * 8],
            Bt + (size_t)(n0 + h * 128 + c * 64 + srow) * K + k0 + gc);
  };

  const floatx4 fz = {0.f, 0.f, 0.f, 0.f};
  floatx4 acc[2][2][2][4];
#pragma unroll
  for (int a = 0; a < 2; ++a)
#pragma unroll
    for (int b = 0; b < 2; ++b)
#pragma unroll
      for (int c = 0; c < 2; ++c)
#pragma unroll
        for (int d = 0; d < 4; ++d) acc[a][b][c][d] = fz;

  short8 af[2][2], bf0[4][2], bf1[4][2];
  const int swz = l16 & 7;

  // prologue: stage tile 0 in need order; wait A0,B0 (leave B1,A1 in flight)
  stageA(0, 0, 0);
  stageB(0, 0, 0);
  stageB(0, 1, 0);
  stageA(0, 1, 0);
  VMW(4);
  GBAR();

  const int NT = K >> 6;
  for (int t = 0; t < NT; ++t) {
    const int buf = t & 1;
    const int kn = (t + 1) << 6;
    const bool pre = (t + 1 < NT);

    // ---- phase 0: quadrant (0,0) ----
    G8_LDA(0);
    G8_LDB(bf0, 0);
    if (pre) stageA(buf ^ 1, 0, kn);
    GBAR();
    G8_MFMA(0, bf0, 0);
    if (pre) { VMW(4); } else { VMW(2); }   // B1(t) landed
    GBAR();

    // ---- phase 1: quadrant (0,1) ----
    G8_LDB(bf1, 1);
    if (pre) stageB(buf ^ 1, 0, kn);
    GBAR();
    G8_MFMA(0, bf1, 1);
    if (pre) { VMW(4); } else { VMW(0); }   // A1(t) landed
    GBAR();

    // ---- phase 2: quadrant (1,0) ----
    G8_LDA(1);
    if (pre) stageB(buf ^ 1, 1, kn);
    GBAR();
    G8_MFMA(1, bf0, 0);
    GBAR();

    // ---- phase 3: quadrant (1,1) ----
    if (pre) stageA(buf ^ 1, 1, kn);
    GBAR();
    G8_MFMA(1, bf1, 1);
    if (pre) { VMW(4); }                    // A0,B0(t+1) landed
    GBAR();
  }

  // epilogue
#pragma unroll
  for (int mh = 0; mh < 2; ++mh)
#pragma unroll
    for (int mi = 0; mi < 2; ++mi)
#pragma unroll
      for (int rr = 0; rr < 4; ++rr) {
        const long row = m0 + mh * 128 + wr * 32 + mi * 16 + quad * 4 + rr;
#pragma unroll
        for (int nh = 0; nh < 2; ++nh)
#pragma unroll
          for (int ni = 0; ni < 4; ++ni) {
            const long col = n0 + nh * 128 + wc * 64 + ni * 16 + l16;
            if constexpr (std::is_same<OutT, float>::value)
              C[row * N + col] = acc[mh][mi][nh][ni][rr];
            else
              C[row * N + col] = f2bf(acc[mh][mi][nh][ni][rr]);
          }
      }
}

#undef G8_LDA
#undef G8_LDB
#undef G8_MFMA

// ---------------------------------------------------------------------------
// Flash attention v5 (round-6: setprio + defer-max).  Grid 512 blocks
// (XCD head-clustered), 4 waves, 32 q-rows/wave, kv-tile 64,
// DOUBLE-BUFFERED K/V (80 KB LDS, 2 blocks/CU).
// ---------------------------------------------------------------------------
__global__ __launch_bounds__(256, 2) void flash_attn(const u16* __restrict__ Q,
                                                     const u16* __restrict__ KV,
                                                     const u16* __restrict__ VT,
                                                     u16* __restrict__ O) {
  __shared__ u16 Ks[2][64 * 128];    // [kv][16 chunks], chunk^= (kv&15)
  __shared__ u16 Vs[2][128 * 64];    // [d][8 chunks],   chunk^= (d&7)
  __shared__ u16 Ps[4][32 * 64];     // per-wave [q][8 chunks], chunk^=((q&7)^(q>>3))
  const int tid = threadIdx.x;
  const int wave = tid >> 6, lane = tid & 63, l16 = lane & 15, quad = lane >> 4;
  const int d = blockIdx.x;
  const int bh = (d & 7) * 4 + ((d >> 3) & 3);
  const int qt = d >> 5;
  const int b = bh >> 4, h = bh & 15;
  const u16* Qb = Q + (size_t)b * 2048 * 2048 + h * 128;
  const u16* Kb = KV + (size_t)b * 2048 * 4096 + h * 128;
  const u16* Vb = VT + (size_t)bh * 128 * 2048;
  u16* Ob = O + (size_t)b * 2048 * 2048 + h * 128;
  const int q0 = qt * 128 + wave * 32;

  short8 qf[2][4];
#pragma unroll
  for (int t = 0; t < 2; ++t)
#pragma unroll
    for (int kd = 0; kd < 4; ++kd)
      qf[t][kd] = *(const short8*)&Qb[(size_t)(q0 + t * 16 + l16) * 2048 + kd * 32 + quad * 8];

  short8 onesf;
  {
    union { short8 s; u32 w[4]; } uo;
    const u32 o = (l16 == 0) ? 0x3F803F80u : 0u;
#pragma unroll
    for (int i = 0; i < 4; ++i) uo.w[i] = o;
    onesf = uo.s;
  }

  const floatx4 fz = {0.f, 0.f, 0.f, 0.f};
  floatx4 oacc[2][9];
  float m[2][4];
#pragma unroll
  for (int t = 0; t < 2; ++t) {
#pragma unroll
    for (int jd = 0; jd < 9; ++jd) oacc[t][jd] = fz;
#pragma unroll
    for (int r = 0; r < 4; ++r) m[t][r] = -1e30f;
  }

  u16* Psw = Ps[wave];
  const float sc2 = 0.12751775f;   // (1/sqrt(128)) * log2(e)
  const float THR2 = 11.5416f;     // defer-max threshold 8 (ln) in log2 space

  auto stage = [&](int buf, int kv0) {
#pragma unroll
    for (int c = 0; c < 4; ++c) {
      const int li = c * 256 + tid;
      const int krow = li >> 4, kdb = (li & 15) ^ (krow & 15);
      gld16(&Ks[buf][li * 8], Kb + (size_t)(kv0 + krow) * 4096 + kdb * 8);
      const int vrow = li >> 3, vdb = (li & 7) ^ (vrow & 7);
      gld16(&Vs[buf][li * 8], Vb + (size_t)vrow * 2048 + kv0 + vdb * 8);
    }
  };

  stage(0, 0);
  int cur = 0;

  for (int kt = 0; kt < 32; ++kt) {
    __syncthreads();
    if (kt < 31) stage(cur ^ 1, (kt + 1) * 64);
    const u16* Kc = Ks[cur];
    const u16* Vc = Vs[cur];

    floatx4 sacc[2][4];
#pragma unroll
    for (int t = 0; t < 2; ++t)
#pragma unroll
      for (int jn = 0; jn < 4; ++jn) sacc[t][jn] = fz;
    __builtin_amdgcn_s_setprio(1);
#pragma unroll
    for (int jn = 0; jn < 4; ++jn)
#pragma unroll
      for (int kd = 0; kd < 4; ++kd) {
        short8 kb = *(const short8*)&Kc[(jn * 16 + l16) * 128 + ((4 * kd + quad) ^ l16) * 8];
        sacc[0][jn] = __builtin_amdgcn_mfma_f32_16x16x32_bf16(qf[0][kd], kb, sacc[0][jn], 0, 0, 0);
        sacc[1][jn] = __builtin_amdgcn_mfma_f32_16x16x32_bf16(qf[1][kd], kb, sacc[1][jn], 0, 0, 0);
      }
    __builtin_amdgcn_s_setprio(0);

#pragma unroll
    for (int t = 0; t < 2; ++t) {
#pragma unroll
      for (int r = 0; r < 4; ++r) {
        float mx = fmaxf(fmaxf(sacc[t][0][r], sacc[t][1][r]),
                         fmaxf(sacc[t][2][r], sacc[t][3][r]));
#pragma unroll
        for (int off = 8; off > 0; off >>= 1) mx = fmaxf(mx, __shfl_xor(mx, off, 16));
        const float mxs = sc2 * mx;
        if (!__all(mxs - m[t][r] <= THR2)) {
          const float mnew = fmaxf(m[t][r], mxs);
          const float alpha = __builtin_amdgcn_exp2f(m[t][r] - mnew);
          m[t][r] = mnew;
#pragma unroll
          for (int jd = 0; jd < 9; ++jd) oacc[t][jd][r] *= alpha;
        }
        const float mrow = m[t][r];
        const int q = t * 16 + quad * 4 + r;               // 0..31
        const int mask = (q & 7) ^ (q >> 3);
        u16* prow = &Psw[q * 64 + (l16 & 7)];
#pragma unroll
        for (int jn = 0; jn < 4; ++jn) {
          const float p = __builtin_amdgcn_exp2f(fmaf(sc2, sacc[t][jn][r], -mrow));
          const int slot = (2 * jn + (l16 >> 3)) ^ mask;
          prow[slot * 8] = f2bf(p);
        }
      }
    }

    const int pmask0 = (l16 & 7) ^ (l16 >> 3);        // t=0
    const int pmask1 = (l16 & 7) ^ (2 + (l16 >> 3));  // t=1
    __builtin_amdgcn_s_setprio(1);
#pragma unroll
    for (int kk = 0; kk < 2; ++kk) {
      const int chunk = 4 * kk + quad;
      short8 pf0 = *(const short8*)&Psw[(l16) * 64 + (chunk ^ pmask0) * 8];
      short8 pf1 = *(const short8*)&Psw[(16 + l16) * 64 + (chunk ^ pmask1) * 8];
#pragma unroll
      for (int jd = 0; jd < 8; ++jd) {
        short8 vb = *(const short8*)&Vc[(jd * 16 + l16) * 64 + (chunk ^ (l16 & 7)) * 8];
        oacc[0][jd] = __builtin_amdgcn_mfma_f32_16x16x32_bf16(pf0, vb, oacc[0][jd], 0, 0, 0);
        oacc[1][jd] = __builtin_amdgcn_mfma_f32_16x16x32_bf16(pf1, vb, oacc[1][jd], 0, 0, 0);
      }
      oacc[0][8] = __builtin_amdgcn_mfma_f32_16x16x32_bf16(pf0, onesf, oacc[0][8], 0, 0, 0);
      oacc[1][8] = __builtin_amdgcn_mfma_f32_16x16x32_bf16(pf1, onesf, oacc[1][8], 0, 0, 0);
    }
    __builtin_amdgcn_s_setprio(0);
    cur ^= 1;
  }

#pragma unroll
  for (int t = 0; t < 2; ++t)
#pragma unroll
    for (int r = 0; r < 4; ++r) {
      const float l = __shfl(oacc[t][8][r], lane & 48);
      const float inv = 1.f / l;
      const size_t row = q0 + t * 16 + quad * 4 + r;
#pragma unroll
      for (int jd = 0; jd < 8; ++jd)
        Ob[row * 2048 + jd * 16 + l16] = f2bf(oacc[t][jd][r] * inv);
    }
}

// ---------------------------------------------------------------------------
extern "C" void kernel_launch(void* const* d_in, const int* in_sizes, int n_in,
                              void* d_out, int out_size, void* d_ws, size_t ws_size,
                              hipStream_t stream) {
  const float* x       = (const float*)d_in[0];
  const float* latents = (const float*)d_in[1];
  const float* w_q     = (const float*)d_in[2];
  const float* w_kv    = (const float*)d_in[3];
  const float* w_out   = (const float*)d_in[4];
  const float* ln1_g   = (const float*)d_in[5];
  const float* ln1_b   = (const float*)d_in[6];
  const float* ln2_g   = (const float*)d_in[7];
  const float* ln2_b   = (const float*)d_in[8];

  char* ws = (char*)d_ws;
  u16* xn    = (u16*)(ws);              // LN(x)        [dead after kv gemm]
  u16* lnl   = (u16*)(ws + 16777216);   // LN(latents)  [dead after q gemm]
  u16* wqT   = (u16*)(ws + 41943040);
  u16* wkvT  = (u16*)(ws + 54525952);
  u16* woutT = (u16*)(ws + 71303168);
  u16* qb    = (u16*)(ws + 83886080);
  u16* kvb   = (u16*)(ws + 100663296);
  u16* vTb   = lnl;                     // alias
  u16* attn  = xn;                      // alias

  ln_cast<2048><<<dim3(4096), 256, 0, stream>>>(x, ln1_g, ln1_b, xn);
  ln_cast<3072><<<dim3(4096), 256, 0, stream>>>(latents, ln2_g, ln2_b, lnl);

  transpose_cast<<<dim3(64, 96), dim3(32, 8), 0, stream>>>(w_q, wqT, 3072, 2048);
  transpose_cast<<<dim3(128, 64), dim3(32, 8), 0, stream>>>(w_kv, wkvT, 2048, 4096);
  transpose_cast<<<dim3(96, 64), dim3(32, 8), 0, stream>>>(w_out, woutT, 2048, 3072);

  gemm_bt<u16><<<dim3(16, 32), 256, 0, stream>>>(lnl, wqT, qb, 4096, 2048, 3072);
  gemm_bt8<u16><<<dim3(16, 16), 512, 0, stream>>>(xn, wkvT, kvb, 4096, 4096, 2048);

  transpose_v<<<dim3(4, 64, 32), dim3(32, 8), 0, stream>>>(kvb, vTb);

  flash_attn<<<dim3(512), 256, 0, stream>>>(qb, kvb, vTb, attn);

  gemm_bt8<float><<<dim3(12, 16), 512, 0, stream>>>(attn, woutT, (float*)d_out, 4096, 3072, 2048);
}